// Round 6
// baseline (12528.591 us; speedup 1.0000x reference)
//
#include <hip/hip_runtime.h>

// ---------------------------------------------------------------------------
// QMon (monDEQ) full pipeline, fp32.
//  conv1(8x8,s4)+relu -> conv2(4x4,s2)+relu -> monDEQ PR solver (freq domain)
//  -> border crop -> fc1+relu -> fc2
// Round 6: persistent solver with MANUAL grid barrier (no cooperative API),
//          512 blocks x 256 thr (capacity-safe co-residency), u12 in LDS;
//          parity-split conv2 LDS (bank-conflict fix).
// ---------------------------------------------------------------------------

#define NB 256
#define NCH 64
#define NP 81
#define NIMG (NB*NCH)
#define MAXIT 50
#define NCAN 41                       // canonical freqs: {0..4} U {9..44}
#define CANON(l) ((l) < 5 ? (l) : (l) + 4)
#define NBLK 512

__constant__ float COS9[9] = {
  1.0f, 0.76604444311897803f, 0.17364817766693041f, -0.5f,
  -0.93969262078590843f, -0.93969262078590843f, -0.5f,
  0.17364817766693041f, 0.76604444311897803f };
__constant__ float SIN9[9] = {
  0.0f, 0.64278760968653936f, 0.98480775301220802f, 0.86602540378443871f,
  0.34202014332566877f, -0.34202014332566877f, -0.86602540378443871f,
  -0.98480775301220802f, -0.64278760968653936f };

// ---------------- manual grid barrier (device-scope atomics) ----------------
// bar[0] = arrive count, bar[1] = generation. All blocks call with identical
// gen sequence. Last arriver resets count and releases gen+1.
__device__ __forceinline__ void gbar(int* bar, int gen) {
    __syncthreads();
    if (threadIdx.x == 0) {
        __threadfence();                               // release my data
        int arrived = __hip_atomic_fetch_add(&bar[0], 1, __ATOMIC_ACQ_REL,
                                             __HIP_MEMORY_SCOPE_AGENT);
        if (arrived == NBLK - 1) {
            __hip_atomic_store(&bar[0], 0, __ATOMIC_RELAXED,
                               __HIP_MEMORY_SCOPE_AGENT);
            __hip_atomic_store(&bar[1], gen + 1, __ATOMIC_RELEASE,
                               __HIP_MEMORY_SCOPE_AGENT);
        } else {
            while (__hip_atomic_load(&bar[1], __ATOMIC_ACQUIRE,
                                     __HIP_MEMORY_SCOPE_AGENT) <= gen) {
                __builtin_amdgcn_s_sleep(8);
            }
        }
        __threadfence();                               // acquire others' data
    }
    __syncthreads();
}

// ---------------- norm of A_w ----------------------------------------------
__global__ __launch_bounds__(256) void k_norm(const float* __restrict__ Aw,
                                              float* __restrict__ sc) {
    __shared__ float red[256];
    float s = 0.f;
    for (int i = threadIdx.x; i < 64*64*9; i += 256) { float a = Aw[i]; s += a*a; }
    red[threadIdx.x] = s; __syncthreads();
    for (int w = 128; w > 0; w >>= 1) {
        if (threadIdx.x < w) red[threadIdx.x] += red[threadIdx.x + w];
        __syncthreads();
    }
    if (threadIdx.x == 0) { float n = sqrtf(red[0]); sc[0] = n; sc[1] = 1.f/n; }
}

// ---------------- conv1: (256,4,84,84)->(256,32,20,20), k8 s4, relu, x/255 --
__global__ __launch_bounds__(512) void k_conv1(const float* __restrict__ x,
                                               const float* __restrict__ w,
                                               const float* __restrict__ bb,
                                               float* __restrict__ y) {
    __shared__ float xl[2*7056];
    int b = blockIdx.x, tid = threadIdx.x;
    float acc[32];
    #pragma unroll
    for (int o = 0; o < 32; ++o) acc[o] = 0.f;
    int p = tid, oy = p/20, ox = p%20;
    for (int cp = 0; cp < 2; ++cp) {
        __syncthreads();
        const float4* xg = (const float4*)(x + b*28224 + cp*14112);
        for (int i = tid; i < 3528; i += 512) ((float4*)xl)[i] = xg[i];
        __syncthreads();
        if (p < 400) {
            #pragma unroll
            for (int ci = 0; ci < 2; ++ci)
            #pragma unroll
            for (int ky = 0; ky < 8; ++ky) {
                const float* xr = xl + ci*7056 + (oy*4+ky)*84 + ox*4;
                float4 x0 = *(const float4*)xr;
                float4 x1 = *(const float4*)(xr+4);
                const float* wr = w + (cp*2+ci)*64 + ky*8;
                #pragma unroll
                for (int o = 0; o < 32; ++o) {
                    const float* wo = wr + o*256;
                    acc[o] += x0.x*wo[0] + x0.y*wo[1] + x0.z*wo[2] + x0.w*wo[3]
                            + x1.x*wo[4] + x1.y*wo[5] + x1.z*wo[6] + x1.w*wo[7];
                }
            }
        }
    }
    if (p < 400) {
        #pragma unroll
        for (int o = 0; o < 32; ++o)
            y[b*12800 + o*400 + p] = fmaxf(acc[o]*(1.f/255.f) + bb[o], 0.f);
    }
}

// ---------------- fused conv2 + circular bias conv --------------------------
// parity-split staging: hl[ci*400 + ((iy&1)*2+(ix&1))*100 + (iy>>1)*10 + (ix>>1)]
// makes conv2's stride-2 taps stride-1 in LDS.
__global__ __launch_bounds__(512) void k_cvb(const float* __restrict__ h1,
                                             const float* __restrict__ w2,
                                             const float* __restrict__ b2,
                                             const float* __restrict__ Uw,
                                             const float* __restrict__ Ub,
                                             float* __restrict__ bias) {
    int b = blockIdx.x, tid = threadIdx.x;
    __shared__ float hl[12800];
    __shared__ float h2l[5184];
    for (int i = tid; i < 12800; i += 512) {
        int ci = i / 400, pix = i % 400, iy = pix / 20, ix = pix % 20;
        hl[ci*400 + ((iy&1)*2 + (ix&1))*100 + (iy>>1)*10 + (ix>>1)] = h1[b*12800 + i];
    }
    __syncthreads();
    for (int idx = tid; idx < 5184; idx += 512) {
        int o = idx/81, p = idx%81, oy = p/9, ox = p%9;
        float acc = 0.f;
        const float* wo = w2 + o*512;
        for (int ci = 0; ci < 32; ci++) {
            const float* base = hl + ci*400;
            const float* wb = wo + ci*16;
            #pragma unroll
            for (int ky = 0; ky < 4; ky++)
            #pragma unroll
            for (int kx = 0; kx < 4; kx++)
                acc += base[((ky&1)*2 + (kx&1))*100 + (oy + (ky>>1))*10 + (ox + (kx>>1))]
                     * wb[ky*4 + kx];
        }
        h2l[idx] = fmaxf(acc + b2[o], 0.f);
    }
    __syncthreads();
    for (int idx = tid; idx < 5184; idx += 512) {
        int o = idx/81, p = idx%81, i0 = p/9, j0 = p%9;
        int im = (i0+8)%9, ip = (i0+1)%9, jm = (j0+8)%9, jp = (j0+1)%9;
        int r0 = im*9, r1 = i0*9, r2 = ip*9;
        float acc = 0.f;
        const float* wo = Uw + o*576;
        for (int ci = 0; ci < 64; ci++) {
            const float* hb = h2l + ci*81;
            const float* wb = wo + ci*9;
            acc += hb[r0+jm]*wb[0] + hb[r0+j0]*wb[1] + hb[r0+jp]*wb[2]
                 + hb[r1+jm]*wb[3] + hb[r1+j0]*wb[4] + hb[r1+jp]*wb[5]
                 + hb[r2+jm]*wb[6] + hb[r2+j0]*wb[7] + hb[r2+jp]*wb[8];
        }
        bias[b*5184 + idx] = acc + Ub[o];
    }
}

// ---------------- Af(f) for canonical f only -------------------------------
__global__ __launch_bounds__(256) void k_af(const float* __restrict__ Aw,
                                            const float* __restrict__ sc,
                                            float2* __restrict__ Af) {
    int l = blockIdx.x; int f = CANON(l);
    int x = f/9, y = f%9;
    float inv = sc[1];
    for (int pr = threadIdx.x; pr < 4096; pr += 256) {
        const float* a = Aw + pr*9;
        float re = 0.f, im = 0.f;
        #pragma unroll
        for (int dx = 0; dx < 3; dx++)
        #pragma unroll
        for (int dy = 0; dy < 3; dy++) {
            int tt = (x*(dx+8) + y*(dy+8)) % 9;
            float v = a[dx*3+dy] * inv;
            re += v * COS9[tt]; im += v * SIN9[tt];
        }
        Af[f*4096 + pr] = make_float2(re, im);
    }
}

// ---------------- M = 1.1 I + g A^H A ; W^T = (0.9 I - g A^H A)^T ----------
__global__ __launch_bounds__(256) void k_mw(const float2* __restrict__ Af,
                                            const float* __restrict__ gp,
                                            float2* __restrict__ Mmat,
                                            float2* __restrict__ WmT) {
    int l = blockIdx.x; int f = CANON(l);
    float g = gp[0];
    __shared__ float2 Al[4096];
    for (int i = threadIdx.x; i < 4096; i += 256) Al[i] = Af[f*4096 + i];
    __syncthreads();
    for (int e = threadIdx.x; e < 4096; e += 256) {
        int i = e >> 6, j = e & 63;
        float sr = 0.f, si = 0.f;
        for (int o = 0; o < 64; o++) {
            float2 a = Al[o*64 + i], b = Al[o*64 + j];
            sr += a.x*b.x + a.y*b.y;
            si += a.x*b.y - a.y*b.x;
        }
        Mmat[f*4096 + e] = make_float2((i==j ? 1.1f : 0.f) + g*sr, g*si);
        WmT [f*4096 + j*64 + i] = make_float2((i==j ? 0.9f : 0.f) - g*sr, -g*si);
    }
}

// ---------------- in-place Gauss-Jordan inverse, conflict-free -------------
__global__ __launch_bounds__(256) void k_inv(float2* __restrict__ Mio) {
    int l = blockIdx.x; int f = CANON(l);
    __shared__ float2 M[64*65];
    __shared__ float2 rowk[64];
    __shared__ float2 fcol[64];
    int tid = threadIdx.x;
    float2* Mg = Mio + f*4096;
    for (int e = tid; e < 4096; e += 256) M[(e>>6)*65 + (e&63)] = Mg[e];
    __syncthreads();
    int j = tid & 63, ig = tid >> 6;
    for (int k = 0; k < 64; k++) {
        if (ig == 0) {
            float2 d = M[k*65 + k];
            float den = 1.f / (d.x*d.x + d.y*d.y);
            float pr = d.x*den, pi = -d.y*den;
            float2 m = M[k*65 + j];
            rowk[j] = (j == k) ? make_float2(pr, pi)
                               : make_float2(m.x*pr - m.y*pi, m.x*pi + m.y*pr);
        } else if (ig == 1) {
            fcol[j] = M[j*65 + k];
        }
        __syncthreads();
        #pragma unroll 4
        for (int s = 0; s < 16; s++) {
            int i = (ig << 4) + s;
            if (i == k) {
                M[i*65 + j] = rowk[j];
            } else {
                float2 fi = fcol[i];
                if (j == k) {
                    float2 rk = rowk[k];
                    M[i*65 + j] = make_float2(-(fi.x*rk.x - fi.y*rk.y),
                                              -(fi.x*rk.y + fi.y*rk.x));
                } else {
                    float2 r = rowk[j]; float2 m = M[i*65 + j];
                    M[i*65 + j] = make_float2(m.x - (fi.x*r.x - fi.y*r.y),
                                              m.y - (fi.x*r.y + fi.y*r.x));
                }
            }
        }
        __syncthreads();
    }
    for (int e = tid; e < 4096; e += 256) {
        int i2 = e >> 6, j2 = e & 63;
        Mio[f*4096 + j2*64 + i2] = M[i2*65 + j2];
    }
}

// ---------------- persistent PR solver, manual grid barrier ----------------
// 512 blocks x 256 thr. Block owns 32 images (2 halves of 16); u12 in LDS.
// Phase A: 656 matvec units (41 freq x 16 batch-chunks), unit = bid, bid+512.
// Phase B: per half: IFFT + PR update + FFT (round-4 k_fuse bodies).
__global__ __launch_bounds__(256, 2) void k_pr(const float* __restrict__ bias,
                                               const float2* __restrict__ Vm,
                                               const float2* __restrict__ Wm,
                                               float2* __restrict__ Tf,
                                               float2* __restrict__ Yf,
                                               float* __restrict__ zc,
                                               int* bar) {
    __shared__ float2 Yc[16*81];
    __shared__ float2 T1[16*81];
    __shared__ float  u12l[32*81];
    __shared__ float2 tw81[81];
    float* tre = (float*)Yc;                 // alias: real staging buffer
    int tid = threadIdx.x, bid = blockIdx.x;
    int tl = tid & 15, th = tid >> 4;
    int lane = tid & 63;
    int wid = __builtin_amdgcn_readfirstlane(tid >> 6);
    for (int i = tid; i < 81; i += 256) {
        int t = ((i/9)*(i%9)) % 9;
        tw81[i] = make_float2(COS9[t], SIN9[t]);
    }
    __syncthreads();

    // ---- prologue: Tf = FFT(bias) for this block's 32 images, u12 = 0 ----
    for (int half = 0; half < 2; ++half) {
        int img0h = bid*32 + half*16;
        int gb = (img0h + th)*81;
        #pragma unroll
        for (int k = 0; k < 6; ++k) {
            int p = tl + 16*k;
            if (p < 81) { tre[th*81+p] = bias[gb+p]; u12l[(half*16+th)*81+p] = 0.f; }
        }
        __syncthreads();
        #pragma unroll
        for (int k = 0; k < 6; ++k) {                  // FFT stage 1 (image th)
            int idx = tl + 16*k;
            if (idx < 81) {
                int r = idx/9, ky = idx%9;
                float sr = 0.f, si = 0.f;
                #pragma unroll
                for (int xx = 0; xx < 9; ++xx) {
                    float v = tre[th*81 + r*9 + xx];
                    float2 w = tw81[ky*9 + xx];
                    sr += v*w.x; si -= v*w.y;
                }
                T1[th*81 + idx] = make_float2(sr, si);
            }
        }
        __syncthreads();
        #pragma unroll
        for (int k = 0; k < 3; ++k) {                  // FFT stage 2 (image tl)
            int l = th + 16*k;
            if (l < NCAN) {
                int f = CANON(l);
                int kx = f/9, ky = f%9;
                float fr = 0.f, fim = 0.f;
                #pragma unroll
                for (int r = 0; r < 9; ++r) {
                    float2 s = T1[tl*81 + r*9 + ky];
                    float2 w = tw81[kx*9 + r];
                    fr  += s.x*w.x + s.y*w.y;
                    fim += s.y*w.x - s.x*w.y;
                }
                Tf[f*NIMG + img0h + tl] = make_float2(fr, fim);
            }
        }
        __syncthreads();
    }
    int gen = 0;
    gbar(bar, gen); ++gen;

    for (int it = 0; it <= MAXIT; ++it) {
        bool fin  = (it == MAXIT);
        bool last = (it == MAXIT - 1);
        // ---- phase A: Yf = V * Tf, freq-major units ----
        const float2* Vb = fin ? Wm : Vm;
        for (int u = bid; u < NCAN*16; u += NBLK) {
            int l = u >> 4, chunk = u & 15;
            int f = CANON(l);
            int b0 = chunk*16 + wid*4;
            const float2* Vg = Vb + f*4096 + lane;
            const float2* Tg = Tf + f*NIMG + b0*64;
            float2 a0 = make_float2(0.f,0.f), a1 = a0, a2 = a0, a3 = a0;
            #pragma unroll 8
            for (int c = 0; c < 64; ++c) {
                float2 v = Vg[c*64];
                float2 t0 = Tg[c], t1 = Tg[64+c], t2 = Tg[128+c], t3 = Tg[192+c];
                a0.x += v.x*t0.x - v.y*t0.y; a0.y += v.x*t0.y + v.y*t0.x;
                a1.x += v.x*t1.x - v.y*t1.y; a1.y += v.x*t1.y + v.y*t1.x;
                a2.x += v.x*t2.x - v.y*t2.y; a2.y += v.x*t2.y + v.y*t2.x;
                a3.x += v.x*t3.x - v.y*t3.y; a3.y += v.x*t3.y + v.y*t3.x;
            }
            float2* Yg = Yf + f*NIMG + b0*64 + lane;
            Yg[0] = a0; Yg[64] = a1; Yg[128] = a2; Yg[192] = a3;
        }
        gbar(bar, gen); ++gen;

        // ---- phase B: per half IFFT + update + FFT (or final crop) ----
        for (int half = 0; half < 2; ++half) {
            int img0h = bid*32 + half*16;
            int gb = (img0h + th)*81;
            #pragma unroll
            for (int k = 0; k < 3; ++k) {              // Yc load + mirrors (img tl)
                int l = th + 16*k;
                if (l < NCAN) {
                    int f = CANON(l);
                    float2 a = Yf[f*NIMG + img0h + tl];
                    Yc[tl*81 + f] = a;
                    int xx = f/9, yy = f%9;
                    int fm = ((9-xx)%9)*9 + (9-yy)%9;
                    if (fm != f) Yc[tl*81 + fm] = make_float2(a.x, -a.y);
                }
            }
            __syncthreads();
            #pragma unroll
            for (int k = 0; k < 6; ++k) {              // IFFT stage 1 (img th)
                int idx = tl + 16*k;
                if (idx < 81) {
                    int r = idx/9, ky = idx%9;
                    float sr = 0.f, si = 0.f;
                    #pragma unroll
                    for (int kx = 0; kx < 9; ++kx) {
                        float2 a = Yc[th*81 + kx*9 + ky];
                        float2 w = tw81[r*9 + kx];
                        sr += a.x*w.x - a.y*w.y;
                        si += a.x*w.y + a.y*w.x;
                    }
                    T1[th*81 + idx] = make_float2(sr, si);
                }
            }
            __syncthreads();
            if (fin) {
                #pragma unroll
                for (int k = 0; k < 6; ++k) {          // final crop (img th)
                    int p = tl + 16*k;
                    if (p < 81) {
                        int r = p/9, xc = p%9;
                        if (r >= 1 && r <= 7 && xc >= 1 && xc <= 7) {
                            float yr = 0.f;
                            #pragma unroll
                            for (int ky = 0; ky < 9; ++ky) {
                                float2 a = T1[th*81 + r*9 + ky];
                                float2 w = tw81[xc*9 + ky];
                                yr += a.x*w.x - a.y*w.y;
                            }
                            yr *= (1.f/81.f);
                            float zv = fmaxf(yr + bias[gb + p], 0.f);
                            int img = img0h + th;
                            zc[(img >> 6)*3136 + (img & 63)*49 + (r-1)*7 + (xc-1)] = zv;
                        }
                    }
                }
                __syncthreads();
                continue;
            }
            #pragma unroll
            for (int k = 0; k < 6; ++k) {              // IFFT stage 2 + PR (img th)
                int p = tl + 16*k;
                if (p < 81) {
                    int r = p/9, xc = p%9;
                    float yr = 0.f;
                    #pragma unroll
                    for (int ky = 0; ky < 9; ++ky) {
                        float2 a = T1[th*81 + r*9 + ky];
                        float2 w = tw81[xc*9 + ky];
                        yr += a.x*w.x - a.y*w.y;
                    }
                    yr *= (1.f/81.f);
                    bool interior = (r >= 1 && r <= 7 && xc >= 1 && xc <= 7);
                    int ui = (half*16 + th)*81 + p;
                    float un = 2.f*yr - u12l[ui];
                    float zn = interior ? fmaxf(un, 0.f) : 0.f;
                    float u12n = 2.f*zn - un;
                    u12l[ui] = u12n;
                    tre[th*81 + p] = last ? zn : (u12n + bias[gb + p]);
                }
            }
            __syncthreads();
            #pragma unroll
            for (int k = 0; k < 6; ++k) {              // FFT stage 1 (img th)
                int idx = tl + 16*k;
                if (idx < 81) {
                    int r = idx/9, ky = idx%9;
                    float sr = 0.f, si = 0.f;
                    #pragma unroll
                    for (int xx = 0; xx < 9; ++xx) {
                        float v = tre[th*81 + r*9 + xx];
                        float2 w = tw81[ky*9 + xx];
                        sr += v*w.x; si -= v*w.y;
                    }
                    T1[th*81 + idx] = make_float2(sr, si);
                }
            }
            __syncthreads();
            #pragma unroll
            for (int k = 0; k < 3; ++k) {              // FFT stage 2 (img tl)
                int l = th + 16*k;
                if (l < NCAN) {
                    int f = CANON(l);
                    int kx = f/9, ky = f%9;
                    float fr = 0.f, fim = 0.f;
                    #pragma unroll
                    for (int r = 0; r < 9; ++r) {
                        float2 s = T1[tl*81 + r*9 + ky];
                        float2 w = tw81[kx*9 + r];
                        fr  += s.x*w.x + s.y*w.y;
                        fim += s.y*w.x - s.x*w.y;
                    }
                    Tf[f*NIMG + img0h + tl] = make_float2(fr, fim);
                }
            }
            __syncthreads();
        }
        if (fin) break;
        gbar(bar, gen); ++gen;
    }
}

// ---------------- fc1: (256x3136)x(512x3136)^T + b, relu -------------------
__global__ __launch_bounds__(256) void k_fc1(const float* __restrict__ A,
                                             const float* __restrict__ W,
                                             const float* __restrict__ bb,
                                             float* __restrict__ H) {
    int bt = blockIdx.x >> 5, ot = blockIdx.x & 31;
    int b0 = bt*16, o0 = ot*16;
    __shared__ float At[16][65], Bt[16][65];
    int tid = threadIdx.x;
    int row = tid >> 6, col = tid & 63;
    int tb = tid >> 4, to = tid & 15;
    float acc = 0.f;
    for (int k0 = 0; k0 < 3136; k0 += 64) {
        #pragma unroll
        for (int s = 0; s < 4; s++) {
            int rr = row + s*4;
            At[rr][col] = A[(b0+rr)*3136 + k0 + col];
            Bt[rr][col] = W[(o0+rr)*3136 + k0 + col];
        }
        __syncthreads();
        #pragma unroll
        for (int kk = 0; kk < 64; kk++)
            acc += At[tb][kk] * Bt[to][kk];
        __syncthreads();
    }
    H[(b0+tb)*512 + o0+to] = fmaxf(acc + bb[o0+to], 0.f);
}

// ---------------- fc2: (256x512)x(18x512)^T + b ----------------------------
__global__ __launch_bounds__(256) void k_fc2(const float* __restrict__ H,
                                             const float* __restrict__ W,
                                             const float* __restrict__ bb,
                                             float* __restrict__ out) {
    int idx = blockIdx.x*256 + threadIdx.x;
    if (idx >= 4608) return;
    int b = idx/18, o = idx%18;
    const float* h = H + b*512;
    const float* w = W + o*512;
    float acc = 0.f;
    for (int k = 0; k < 512; k++) acc += h[k]*w[k];
    out[idx] = acc + bb[o];
}

// ---------------------------------------------------------------------------
extern "C" void kernel_launch(void* const* d_in, const int* in_sizes, int n_in,
                              void* d_out, int out_size, void* d_ws, size_t ws_size,
                              hipStream_t stream) {
    (void)in_sizes; (void)n_in; (void)out_size; (void)ws_size;
    const float* x   = (const float*)d_in[0];
    const float* c1w = (const float*)d_in[1];
    const float* c1b = (const float*)d_in[2];
    const float* c2w = (const float*)d_in[3];
    const float* c2b = (const float*)d_in[4];
    const float* Uw  = (const float*)d_in[5];
    const float* Ub  = (const float*)d_in[6];
    const float* Aw  = (const float*)d_in[7];
    const float* gp  = (const float*)d_in[8];
    const float* f1w = (const float*)d_in[9];
    const float* f1b = (const float*)d_in[10];
    const float* f2w = (const float*)d_in[11];
    const float* f2b = (const float*)d_in[12];

    float* ws = (float*)d_ws;
    float*  h1   = ws + 0;                       // 3,276,800 f
    float2* Tf   = (float2*)(ws + 0);            // alias h1 (dead after k_cvb)
    float*  bias = ws + 3276800;                 // 1,327,104 f
    float2* Yf   = (float2*)(ws + 4603904);      // 1,327,104 c2
    float2* Af   = (float2*)(ws + 7258112);      // 331,776 c2
    float2* Minv = (float2*)(ws + 7921664);      // 331,776 c2
    float2* WmT  = (float2*)(ws + 8585216);      // 331,776 c2
    float*  zc   = ws + 9248768;                 // 802,816 f
    float*  hfc  = ws + 10051584;                // 131,072 f
    float*  sc   = ws + 10182656;                // 2 f
    int*    bar  = (int*)(ws + 10182658);        // 2 ints

    hipMemsetAsync(bar, 0, 2*sizeof(int), stream);

    k_norm <<<1,   256, 0, stream>>>(Aw, sc);
    k_conv1<<<256, 512, 0, stream>>>(x, c1w, c1b, h1);
    k_cvb  <<<256, 512, 0, stream>>>(h1, c2w, c2b, Uw, Ub, bias);
    k_af   <<<NCAN,256, 0, stream>>>(Aw, sc, Af);
    k_mw   <<<NCAN,256, 0, stream>>>(Af, gp, Minv, WmT);
    k_inv  <<<NCAN,256, 0, stream>>>(Minv);

    k_pr<<<NBLK, 256, 0, stream>>>(bias, Minv, WmT, Tf, Yf, zc, bar);

    k_fc1<<<512,256,0,stream>>>(zc, f1w, f1b, hfc);
    k_fc2<<<18, 256,0,stream>>>(hfc, f2w, f2b, (float*)d_out);
}

// Round 7
// 2377.648 us; speedup vs baseline: 5.2693x; 5.2693x over previous
//
#include <hip/hip_runtime.h>

// ---------------------------------------------------------------------------
// QMon (monDEQ) full pipeline, fp32.
//  conv1(8x8,s4)+relu -> conv2(4x4,s2)+relu -> monDEQ PR solver (freq domain)
//  -> border crop -> fc1+relu -> fc2
// Round 7: R4 split structure + register-blocked FFT kernels:
//   - k_fuse: 3 phases, constexpr twiddles, IFFT2+PR+FFT1 fused in registers
//   - z array & final k_fft removed (last k_fuse emits FFT(z))
//   - k_mv / conv1 / parity-split k_cvb unchanged (proven).
// ---------------------------------------------------------------------------

#define NB 256
#define NCH 64
#define NP 81
#define NIMG (NB*NCH)
#define MAXIT 50
#define NCAN 41                       // canonical freqs: {0..4} U {9..44}
#define CANON(l) ((l) < 5 ? (l) : (l) + 4)

// compile-time twiddles: C9[m] = cos(2*pi*m/9), S9[m] = sin(2*pi*m/9)
constexpr float C9[9] = {
  1.0f, 0.76604444311897803f, 0.17364817766693041f, -0.5f,
  -0.93969262078590843f, -0.93969262078590843f, -0.5f,
  0.17364817766693041f, 0.76604444311897803f };
constexpr float S9[9] = {
  0.0f, 0.64278760968653936f, 0.98480775301220802f, 0.86602540378443871f,
  0.34202014332566877f, -0.34202014332566877f, -0.86602540378443871f,
  -0.98480775301220802f, -0.64278760968653936f };

__constant__ float COS9[9] = {
  1.0f, 0.76604444311897803f, 0.17364817766693041f, -0.5f,
  -0.93969262078590843f, -0.93969262078590843f, -0.5f,
  0.17364817766693041f, 0.76604444311897803f };
__constant__ float SIN9[9] = {
  0.0f, 0.64278760968653936f, 0.98480775301220802f, 0.86602540378443871f,
  0.34202014332566877f, -0.34202014332566877f, -0.86602540378443871f,
  -0.98480775301220802f, -0.64278760968653936f };

// ---------------- norm of A_w ----------------------------------------------
__global__ __launch_bounds__(256) void k_norm(const float* __restrict__ Aw,
                                              float* __restrict__ sc) {
    __shared__ float red[256];
    float s = 0.f;
    for (int i = threadIdx.x; i < 64*64*9; i += 256) { float a = Aw[i]; s += a*a; }
    red[threadIdx.x] = s; __syncthreads();
    for (int w = 128; w > 0; w >>= 1) {
        if (threadIdx.x < w) red[threadIdx.x] += red[threadIdx.x + w];
        __syncthreads();
    }
    if (threadIdx.x == 0) { float n = sqrtf(red[0]); sc[0] = n; sc[1] = 1.f/n; }
}

// ---------------- conv1: (256,4,84,84)->(256,32,20,20), k8 s4, relu, x/255 --
__global__ __launch_bounds__(512) void k_conv1(const float* __restrict__ x,
                                               const float* __restrict__ w,
                                               const float* __restrict__ bb,
                                               float* __restrict__ y) {
    __shared__ float xl[2*7056];
    int b = blockIdx.x, tid = threadIdx.x;
    float acc[32];
    #pragma unroll
    for (int o = 0; o < 32; ++o) acc[o] = 0.f;
    int p = tid, oy = p/20, ox = p%20;
    for (int cp = 0; cp < 2; ++cp) {
        __syncthreads();
        const float4* xg = (const float4*)(x + b*28224 + cp*14112);
        for (int i = tid; i < 3528; i += 512) ((float4*)xl)[i] = xg[i];
        __syncthreads();
        if (p < 400) {
            #pragma unroll
            for (int ci = 0; ci < 2; ++ci)
            #pragma unroll
            for (int ky = 0; ky < 8; ++ky) {
                const float* xr = xl + ci*7056 + (oy*4+ky)*84 + ox*4;
                float4 x0 = *(const float4*)xr;
                float4 x1 = *(const float4*)(xr+4);
                const float* wr = w + (cp*2+ci)*64 + ky*8;
                #pragma unroll
                for (int o = 0; o < 32; ++o) {
                    const float* wo = wr + o*256;
                    acc[o] += x0.x*wo[0] + x0.y*wo[1] + x0.z*wo[2] + x0.w*wo[3]
                            + x1.x*wo[4] + x1.y*wo[5] + x1.z*wo[6] + x1.w*wo[7];
                }
            }
        }
    }
    if (p < 400) {
        #pragma unroll
        for (int o = 0; o < 32; ++o)
            y[b*12800 + o*400 + p] = fmaxf(acc[o]*(1.f/255.f) + bb[o], 0.f);
    }
}

// ---------------- fused conv2 + circular bias conv (parity-split LDS) -------
__global__ __launch_bounds__(512) void k_cvb(const float* __restrict__ h1,
                                             const float* __restrict__ w2,
                                             const float* __restrict__ b2,
                                             const float* __restrict__ Uw,
                                             const float* __restrict__ Ub,
                                             float* __restrict__ bias) {
    int b = blockIdx.x, tid = threadIdx.x;
    __shared__ float hl[12800];
    __shared__ float h2l[5184];
    for (int i = tid; i < 12800; i += 512) {
        int ci = i / 400, pix = i % 400, iy = pix / 20, ix = pix % 20;
        hl[ci*400 + ((iy&1)*2 + (ix&1))*100 + (iy>>1)*10 + (ix>>1)] = h1[b*12800 + i];
    }
    __syncthreads();
    for (int idx = tid; idx < 5184; idx += 512) {
        int o = idx/81, p = idx%81, oy = p/9, ox = p%9;
        float acc = 0.f;
        const float* wo = w2 + o*512;
        for (int ci = 0; ci < 32; ci++) {
            const float* base = hl + ci*400;
            const float* wb = wo + ci*16;
            #pragma unroll
            for (int ky = 0; ky < 4; ky++)
            #pragma unroll
            for (int kx = 0; kx < 4; kx++)
                acc += base[((ky&1)*2 + (kx&1))*100 + (oy + (ky>>1))*10 + (ox + (kx>>1))]
                     * wb[ky*4 + kx];
        }
        h2l[idx] = fmaxf(acc + b2[o], 0.f);
    }
    __syncthreads();
    for (int idx = tid; idx < 5184; idx += 512) {
        int o = idx/81, p = idx%81, i0 = p/9, j0 = p%9;
        int im = (i0+8)%9, ip = (i0+1)%9, jm = (j0+8)%9, jp = (j0+1)%9;
        int r0 = im*9, r1 = i0*9, r2 = ip*9;
        float acc = 0.f;
        const float* wo = Uw + o*576;
        for (int ci = 0; ci < 64; ci++) {
            const float* hb = h2l + ci*81;
            const float* wb = wo + ci*9;
            acc += hb[r0+jm]*wb[0] + hb[r0+j0]*wb[1] + hb[r0+jp]*wb[2]
                 + hb[r1+jm]*wb[3] + hb[r1+j0]*wb[4] + hb[r1+jp]*wb[5]
                 + hb[r2+jm]*wb[6] + hb[r2+j0]*wb[7] + hb[r2+jp]*wb[8];
        }
        bias[b*5184 + idx] = acc + Ub[o];
    }
}

// ---------------- Af(f) for canonical f only -------------------------------
__global__ __launch_bounds__(256) void k_af(const float* __restrict__ Aw,
                                            const float* __restrict__ sc,
                                            float2* __restrict__ Af) {
    int l = blockIdx.x; int f = CANON(l);
    int x = f/9, y = f%9;
    float inv = sc[1];
    for (int pr = threadIdx.x; pr < 4096; pr += 256) {
        const float* a = Aw + pr*9;
        float re = 0.f, im = 0.f;
        #pragma unroll
        for (int dx = 0; dx < 3; dx++)
        #pragma unroll
        for (int dy = 0; dy < 3; dy++) {
            int tt = (x*(dx+8) + y*(dy+8)) % 9;
            float v = a[dx*3+dy] * inv;
            re += v * COS9[tt]; im += v * SIN9[tt];
        }
        Af[f*4096 + pr] = make_float2(re, im);
    }
}

// ---------------- M = 1.1 I + g A^H A ; W^T = (0.9 I - g A^H A)^T ----------
__global__ __launch_bounds__(256) void k_mw(const float2* __restrict__ Af,
                                            const float* __restrict__ gp,
                                            float2* __restrict__ Mmat,
                                            float2* __restrict__ WmT) {
    int l = blockIdx.x; int f = CANON(l);
    float g = gp[0];
    __shared__ float2 Al[4096];
    for (int i = threadIdx.x; i < 4096; i += 256) Al[i] = Af[f*4096 + i];
    __syncthreads();
    for (int e = threadIdx.x; e < 4096; e += 256) {
        int i = e >> 6, j = e & 63;
        float sr = 0.f, si = 0.f;
        for (int o = 0; o < 64; o++) {
            float2 a = Al[o*64 + i], b = Al[o*64 + j];
            sr += a.x*b.x + a.y*b.y;
            si += a.x*b.y - a.y*b.x;
        }
        Mmat[f*4096 + e] = make_float2((i==j ? 1.1f : 0.f) + g*sr, g*si);
        WmT [f*4096 + j*64 + i] = make_float2((i==j ? 0.9f : 0.f) - g*sr, -g*si);
    }
}

// ---------------- in-place Gauss-Jordan inverse, conflict-free -------------
__global__ __launch_bounds__(256) void k_inv(float2* __restrict__ Mio) {
    int l = blockIdx.x; int f = CANON(l);
    __shared__ float2 M[64*65];
    __shared__ float2 rowk[64];
    __shared__ float2 fcol[64];
    int tid = threadIdx.x;
    float2* Mg = Mio + f*4096;
    for (int e = tid; e < 4096; e += 256) M[(e>>6)*65 + (e&63)] = Mg[e];
    __syncthreads();
    int j = tid & 63, ig = tid >> 6;
    for (int k = 0; k < 64; k++) {
        if (ig == 0) {
            float2 d = M[k*65 + k];
            float den = 1.f / (d.x*d.x + d.y*d.y);
            float pr = d.x*den, pi = -d.y*den;
            float2 m = M[k*65 + j];
            rowk[j] = (j == k) ? make_float2(pr, pi)
                               : make_float2(m.x*pr - m.y*pi, m.x*pi + m.y*pr);
        } else if (ig == 1) {
            fcol[j] = M[j*65 + k];
        }
        __syncthreads();
        #pragma unroll 4
        for (int s = 0; s < 16; s++) {
            int i = (ig << 4) + s;
            if (i == k) {
                M[i*65 + j] = rowk[j];
            } else {
                float2 fi = fcol[i];
                if (j == k) {
                    float2 rk = rowk[k];
                    M[i*65 + j] = make_float2(-(fi.x*rk.x - fi.y*rk.y),
                                              -(fi.x*rk.y + fi.y*rk.x));
                } else {
                    float2 r = rowk[j]; float2 m = M[i*65 + j];
                    M[i*65 + j] = make_float2(m.x - (fi.x*r.x - fi.y*r.y),
                                              m.y - (fi.x*r.y + fi.y*r.x));
                }
            }
        }
        __syncthreads();
    }
    for (int e = tid; e < 4096; e += 256) {
        int i2 = e >> 6, j2 = e & 63;
        Mio[f*4096 + j2*64 + i2] = M[i2*65 + j2];
    }
}

// ---------------- prologue FFT: Tf = FFT2(bias), register-blocked ----------
__global__ __launch_bounds__(192) void k_fft(const float* __restrict__ in,
                                             float2* __restrict__ Tf) {
    __shared__ float2 T1[16*83];
    int tid = threadIdx.x;
    int img = tid & 15, j = tid >> 4;         // j in [0,12), active j<9
    int gimg = blockIdx.x*16 + img;
    if (j < 9) {                               // FFT stage 1, row r=j
        int r = j;
        float tn[9];
        const float* gp = in + gimg*81 + r*9;
        #pragma unroll
        for (int xc = 0; xc < 9; ++xc) tn[xc] = gp[xc];
        #pragma unroll
        for (int ky = 0; ky < 9; ++ky) {
            float sr = 0.f, si = 0.f;
            #pragma unroll
            for (int xx = 0; xx < 9; ++xx) {
                const int m = (ky*xx) % 9;
                sr += tn[xx]*C9[m];
                si -= tn[xx]*S9[m];
            }
            T1[img*83 + r*9 + ky] = make_float2(sr, si);
        }
    }
    __syncthreads();
    if (j < 9) {                               // FFT stage 2, column ky=j
        int ky = j;
        float2 s[9];
        #pragma unroll
        for (int r = 0; r < 9; ++r) s[r] = T1[img*83 + r*9 + ky];
        #pragma unroll
        for (int kx = 0; kx < 5; ++kx) {
            float fr = 0.f, fi = 0.f;
            #pragma unroll
            for (int r = 0; r < 9; ++r) {
                const int m = (kx*r) % 9;
                fr += s[r].x*C9[m] + s[r].y*S9[m];
                fi += s[r].y*C9[m] - s[r].x*S9[m];
            }
            if (kx > 0 || ky < 5)
                Tf[(kx*9 + ky)*NIMG + gimg] = make_float2(fr, fi);
        }
    }
}

// ---------------- per-frequency matvec, LDS-free (unchanged from R4) -------
__global__ __launch_bounds__(256) void k_mv(const float2* __restrict__ Tf,
                                            float2* __restrict__ Yf,
                                            const float2* __restrict__ V) {
    int l = blockIdx.x >> 3, bc = blockIdx.x & 7;   // 41 freqs x 8 chunks
    int f = CANON(l);
    int lane = threadIdx.x & 63;
    int wid  = __builtin_amdgcn_readfirstlane((int)(threadIdx.x >> 6));
    int b0 = bc*32 + wid*8;                          // 8 batches per wave
    const float2* Vg = V + f*4096 + lane;
    const float2* Tg = Tf + f*NIMG + b0*64;
    float2 acc[8];
    #pragma unroll
    for (int j = 0; j < 8; ++j) acc[j] = make_float2(0.f, 0.f);
    #pragma unroll 4
    for (int c = 0; c < 64; ++c) {
        float2 v = Vg[c*64];
        #pragma unroll
        for (int j = 0; j < 8; ++j) {
            float2 t = Tg[j*64 + c];                 // wave-uniform -> s_load
            acc[j].x += v.x*t.x - v.y*t.y;
            acc[j].y += v.x*t.y + v.y*t.x;
        }
    }
    float2* Yg = Yf + f*NIMG + b0*64 + lane;
    #pragma unroll
    for (int j = 0; j < 8; ++j) Yg[j*64] = acc[j];
}

// ---------------- fused iteration: IFFT2 + PR update + FFT2 ----------------
// 3 register-blocked phases, 2 barriers. Thread (img, j): 16 imgs/block.
__global__ __launch_bounds__(192) void k_fuse(const float2* __restrict__ Yf,
                                              float* __restrict__ u12g,
                                              const float* __restrict__ bias,
                                              float2* __restrict__ Tf,
                                              int last) {
    __shared__ float2 T1[16*83];
    int tid = threadIdx.x;
    int img = tid & 15, j = tid >> 4;
    int gimg = blockIdx.x*16 + img;
    // ---- phase 1: load Yf (mirror conj) + IFFT stage 1, column ky=j ----
    if (j < 9) {
        int ky = j;
        float2 y[9];
        #pragma unroll
        for (int kx = 0; kx < 9; ++kx) {
            int fc; bool cj;
            if (kx == 0)      { cj = (ky >= 5); fc = cj ? (9 - ky) : ky; }
            else if (kx <= 4) { cj = false;     fc = kx*9 + ky; }
            else              { cj = true;      fc = (9-kx)*9 + (ky ? 9-ky : 0); }
            float2 a = Yf[fc*NIMG + gimg];
            y[kx] = make_float2(a.x, cj ? -a.y : a.y);
        }
        #pragma unroll
        for (int r = 0; r < 9; ++r) {
            float sr = 0.f, si = 0.f;
            #pragma unroll
            for (int kx = 0; kx < 9; ++kx) {
                const int m = (r*kx) % 9;
                sr += y[kx].x*C9[m] - y[kx].y*S9[m];
                si += y[kx].x*S9[m] + y[kx].y*C9[m];
            }
            T1[img*83 + r*9 + ky] = make_float2(sr, si);
        }
    }
    __syncthreads();
    // ---- phase 2: IFFT st2 + PR update + FFT st1, row r=j (in-place) ----
    if (j < 9) {
        int r = j;
        float2 t1[9];
        #pragma unroll
        for (int ky = 0; ky < 9; ++ky) t1[ky] = T1[img*83 + r*9 + ky];
        float tn[9];
        int gb = gimg*81 + r*9;
        #pragma unroll
        for (int xc = 0; xc < 9; ++xc) {
            float yr = 0.f;
            #pragma unroll
            for (int ky = 0; ky < 9; ++ky) {
                const int m = (xc*ky) % 9;
                yr += t1[ky].x*C9[m] - t1[ky].y*S9[m];
            }
            yr *= (1.f/81.f);
            float u12v = u12g[gb + xc];
            float un = 2.f*yr - u12v;
            bool interior = (r >= 1 && r <= 7 && xc >= 1 && xc <= 7);
            float zn = interior ? fmaxf(un, 0.f) : 0.f;
            float u12n = 2.f*zn - un;
            u12g[gb + xc] = u12n;
            tn[xc] = last ? zn : (u12n + bias[gb + xc]);
        }
        #pragma unroll
        for (int ky = 0; ky < 9; ++ky) {
            float sr = 0.f, si = 0.f;
            #pragma unroll
            for (int xx = 0; xx < 9; ++xx) {
                const int m = (ky*xx) % 9;
                sr += tn[xx]*C9[m];
                si -= tn[xx]*S9[m];
            }
            T1[img*83 + r*9 + ky] = make_float2(sr, si);
        }
    }
    __syncthreads();
    // ---- phase 3: FFT st2, canonical freqs only, column ky=j ----
    if (j < 9) {
        int ky = j;
        float2 s[9];
        #pragma unroll
        for (int r = 0; r < 9; ++r) s[r] = T1[img*83 + r*9 + ky];
        #pragma unroll
        for (int kx = 0; kx < 5; ++kx) {
            float fr = 0.f, fi = 0.f;
            #pragma unroll
            for (int r = 0; r < 9; ++r) {
                const int m = (kx*r) % 9;
                fr += s[r].x*C9[m] + s[r].y*S9[m];
                fi += s[r].y*C9[m] - s[r].x*S9[m];
            }
            if (kx > 0 || ky < 5)
                Tf[(kx*9 + ky)*NIMG + gimg] = make_float2(fr, fi);
        }
    }
}

// ---------------- final: IFFT(W z + ...) -> relu(+bias) -> crop write ------
__global__ __launch_bounds__(192) void k_crop(const float2* __restrict__ Yf,
                                              const float* __restrict__ bias,
                                              float* __restrict__ zc) {
    __shared__ float2 T1[16*83];
    int tid = threadIdx.x;
    int img = tid & 15, j = tid >> 4;
    int gimg = blockIdx.x*16 + img;
    if (j < 9) {                               // mirror-load + IFFT st1
        int ky = j;
        float2 y[9];
        #pragma unroll
        for (int kx = 0; kx < 9; ++kx) {
            int fc; bool cj;
            if (kx == 0)      { cj = (ky >= 5); fc = cj ? (9 - ky) : ky; }
            else if (kx <= 4) { cj = false;     fc = kx*9 + ky; }
            else              { cj = true;      fc = (9-kx)*9 + (ky ? 9-ky : 0); }
            float2 a = Yf[fc*NIMG + gimg];
            y[kx] = make_float2(a.x, cj ? -a.y : a.y);
        }
        #pragma unroll
        for (int r = 0; r < 9; ++r) {
            float sr = 0.f, si = 0.f;
            #pragma unroll
            for (int kx = 0; kx < 9; ++kx) {
                const int m = (r*kx) % 9;
                sr += y[kx].x*C9[m] - y[kx].y*S9[m];
                si += y[kx].x*S9[m] + y[kx].y*C9[m];
            }
            T1[img*83 + r*9 + ky] = make_float2(sr, si);
        }
    }
    __syncthreads();
    if (j >= 1 && j <= 7) {                    // IFFT st2 + relu + crop, row r=j
        int r = j;
        float2 t1[9];
        #pragma unroll
        for (int ky = 0; ky < 9; ++ky) t1[ky] = T1[img*83 + r*9 + ky];
        int gb = gimg*81 + r*9;
        float* zr = zc + (gimg >> 6)*3136 + (gimg & 63)*49 + (r-1)*7;
        #pragma unroll
        for (int xc = 1; xc < 8; ++xc) {
            float yr = 0.f;
            #pragma unroll
            for (int ky = 0; ky < 9; ++ky) {
                const int m = (xc*ky) % 9;
                yr += t1[ky].x*C9[m] - t1[ky].y*S9[m];
            }
            yr *= (1.f/81.f);
            zr[xc-1] = fmaxf(yr + bias[gb + xc], 0.f);
        }
    }
}

// ---------------- fc1: (256x3136)x(512x3136)^T + b, relu -------------------
__global__ __launch_bounds__(256) void k_fc1(const float* __restrict__ A,
                                             const float* __restrict__ W,
                                             const float* __restrict__ bb,
                                             float* __restrict__ H) {
    int bt = blockIdx.x >> 5, ot = blockIdx.x & 31;
    int b0 = bt*16, o0 = ot*16;
    __shared__ float At[16][65], Bt[16][65];
    int tid = threadIdx.x;
    int row = tid >> 6, col = tid & 63;
    int tb = tid >> 4, to = tid & 15;
    float acc = 0.f;
    for (int k0 = 0; k0 < 3136; k0 += 64) {
        #pragma unroll
        for (int s = 0; s < 4; s++) {
            int rr = row + s*4;
            At[rr][col] = A[(b0+rr)*3136 + k0 + col];
            Bt[rr][col] = W[(o0+rr)*3136 + k0 + col];
        }
        __syncthreads();
        #pragma unroll
        for (int kk = 0; kk < 64; kk++)
            acc += At[tb][kk] * Bt[to][kk];
        __syncthreads();
    }
    H[(b0+tb)*512 + o0+to] = fmaxf(acc + bb[o0+to], 0.f);
}

// ---------------- fc2: (256x512)x(18x512)^T + b ----------------------------
__global__ __launch_bounds__(256) void k_fc2(const float* __restrict__ H,
                                             const float* __restrict__ W,
                                             const float* __restrict__ bb,
                                             float* __restrict__ out) {
    int idx = blockIdx.x*256 + threadIdx.x;
    if (idx >= 4608) return;
    int b = idx/18, o = idx%18;
    const float* h = H + b*512;
    const float* w = W + o*512;
    float acc = 0.f;
    for (int k = 0; k < 512; k++) acc += h[k]*w[k];
    out[idx] = acc + bb[o];
}

// ---------------------------------------------------------------------------
extern "C" void kernel_launch(void* const* d_in, const int* in_sizes, int n_in,
                              void* d_out, int out_size, void* d_ws, size_t ws_size,
                              hipStream_t stream) {
    (void)in_sizes; (void)n_in; (void)out_size; (void)ws_size;
    const float* x   = (const float*)d_in[0];
    const float* c1w = (const float*)d_in[1];
    const float* c1b = (const float*)d_in[2];
    const float* c2w = (const float*)d_in[3];
    const float* c2b = (const float*)d_in[4];
    const float* Uw  = (const float*)d_in[5];
    const float* Ub  = (const float*)d_in[6];
    const float* Aw  = (const float*)d_in[7];
    const float* gp  = (const float*)d_in[8];
    const float* f1w = (const float*)d_in[9];
    const float* f1b = (const float*)d_in[10];
    const float* f2w = (const float*)d_in[11];
    const float* f2b = (const float*)d_in[12];

    float* ws = (float*)d_ws;
    float*  h1   = ws + 0;                       // 3,276,800 f
    float2* Tf   = (float2*)(ws + 0);            // alias h1 (dead after k_cvb)
    float*  bias = ws + 3276800;                 // 1,327,104 f
    float*  u12  = ws + 4603904;                 // 1,327,104 f
    float2* Yf   = (float2*)(ws + 5931008);      // 1,327,104 c2
    float2* Af   = (float2*)(ws + 8585216);      // 331,776 c2
    float2* Minv = (float2*)(ws + 9248768);      // 331,776 c2
    float2* WmT  = (float2*)(ws + 9912320);      // 331,776 c2
    float*  zc   = ws + 10575872;                // 802,816 f
    float*  hfc  = ws + 11378688;                // 131,072 f
    float*  sc   = ws + 11509760;                // 2 f

    hipMemsetAsync(u12, 0, (size_t)1327104*sizeof(float), stream);

    k_norm <<<1,   256, 0, stream>>>(Aw, sc);
    k_conv1<<<256, 512, 0, stream>>>(x, c1w, c1b, h1);
    k_cvb  <<<256, 512, 0, stream>>>(h1, c2w, c2b, Uw, Ub, bias);
    k_af   <<<NCAN,256, 0, stream>>>(Aw, sc, Af);
    k_mw   <<<NCAN,256, 0, stream>>>(Af, gp, Minv, WmT);
    k_inv  <<<NCAN,256, 0, stream>>>(Minv);

    // iteration 0 forward: u12 = 0, so T = FFT(bias)
    k_fft<<<1024,192,0,stream>>>(bias, Tf);
    for (int it = 0; it < MAXIT; it++) {
        k_mv  <<<NCAN*8,256,0,stream>>>(Tf, Yf, Minv);
        k_fuse<<<1024,  192,0,stream>>>(Yf, u12, bias, Tf, it == MAXIT-1);
    }
    // final pass: brelu(W z + bias) -> crop  (Tf already = FFT(z))
    k_mv  <<<NCAN*8,256,0,stream>>>(Tf, Yf, WmT);
    k_crop<<<1024,  192,0,stream>>>(Yf, bias, zc);

    k_fc1<<<512,256,0,stream>>>(zc, f1w, f1b, hfc);
    k_fc2<<<18, 256,0,stream>>>(hfc, f2w, f2b, (float*)d_out);
}

// Round 8
// 1956.114 us; speedup vs baseline: 6.4048x; 1.2155x over previous
//
#include <hip/hip_runtime.h>

// ---------------------------------------------------------------------------
// QMon (monDEQ) full pipeline, fp32.
//  conv1(8x8,s4)+relu -> conv2(4x4,s2)+relu -> monDEQ PR solver (freq domain)
//  -> border crop -> fc1+relu -> fc2
// Round 8: occupancy fixes. conv1 split 2 blocks/image (2 blocks/CU);
//  cvb split into conv2+bias, each grid 512; k_mv 16 chunks/freq.
//  Solver structure unchanged from R7 (proven).
// ---------------------------------------------------------------------------

#define NB 256
#define NCH 64
#define NP 81
#define NIMG (NB*NCH)
#define MAXIT 50
#define NCAN 41                       // canonical freqs: {0..4} U {9..44}
#define CANON(l) ((l) < 5 ? (l) : (l) + 4)

// compile-time twiddles: C9[m] = cos(2*pi*m/9), S9[m] = sin(2*pi*m/9)
constexpr float C9[9] = {
  1.0f, 0.76604444311897803f, 0.17364817766693041f, -0.5f,
  -0.93969262078590843f, -0.93969262078590843f, -0.5f,
  0.17364817766693041f, 0.76604444311897803f };
constexpr float S9[9] = {
  0.0f, 0.64278760968653936f, 0.98480775301220802f, 0.86602540378443871f,
  0.34202014332566877f, -0.34202014332566877f, -0.86602540378443871f,
  -0.98480775301220802f, -0.64278760968653936f };

__constant__ float COS9[9] = {
  1.0f, 0.76604444311897803f, 0.17364817766693041f, -0.5f,
  -0.93969262078590843f, -0.93969262078590843f, -0.5f,
  0.17364817766693041f, 0.76604444311897803f };
__constant__ float SIN9[9] = {
  0.0f, 0.64278760968653936f, 0.98480775301220802f, 0.86602540378443871f,
  0.34202014332566877f, -0.34202014332566877f, -0.86602540378443871f,
  -0.98480775301220802f, -0.64278760968653936f };

// ---------------- norm of A_w ----------------------------------------------
__global__ __launch_bounds__(256) void k_norm(const float* __restrict__ Aw,
                                              float* __restrict__ sc) {
    __shared__ float red[256];
    float s = 0.f;
    for (int i = threadIdx.x; i < 64*64*9; i += 256) { float a = Aw[i]; s += a*a; }
    red[threadIdx.x] = s; __syncthreads();
    for (int w = 128; w > 0; w >>= 1) {
        if (threadIdx.x < w) red[threadIdx.x] += red[threadIdx.x + w];
        __syncthreads();
    }
    if (threadIdx.x == 0) { float n = sqrtf(red[0]); sc[0] = n; sc[1] = 1.f/n; }
}

// ---------------- conv1: (256,4,84,84)->(256,32,20,20), k8 s4, relu, x/255 --
// 2 blocks per image (16 oc each) -> 2 blocks/CU, 16 waves/CU.
__global__ __launch_bounds__(512, 4) void k_conv1(const float* __restrict__ x,
                                                  const float* __restrict__ w,
                                                  const float* __restrict__ bb,
                                                  float* __restrict__ y) {
    __shared__ float xl[2*7056];
    int blk = blockIdx.x, tid = threadIdx.x;
    int b = blk >> 1, og = (blk & 1) << 4;
    float acc[16];
    #pragma unroll
    for (int o = 0; o < 16; ++o) acc[o] = 0.f;
    int p = tid, oy = p/20, ox = p%20;
    for (int cp = 0; cp < 2; ++cp) {
        __syncthreads();
        const float4* xg = (const float4*)(x + b*28224 + cp*14112);
        for (int i = tid; i < 3528; i += 512) ((float4*)xl)[i] = xg[i];
        __syncthreads();
        if (p < 400) {
            #pragma unroll
            for (int ci = 0; ci < 2; ++ci)
            #pragma unroll
            for (int ky = 0; ky < 8; ++ky) {
                const float* xr = xl + ci*7056 + (oy*4+ky)*84 + ox*4;
                float4 x0 = *(const float4*)xr;
                float4 x1 = *(const float4*)(xr+4);
                const float* wr = w + og*256 + (cp*2+ci)*64 + ky*8;
                #pragma unroll
                for (int o = 0; o < 16; ++o) {
                    const float* wo = wr + o*256;            // uniform -> s_load
                    acc[o] += x0.x*wo[0] + x0.y*wo[1] + x0.z*wo[2] + x0.w*wo[3]
                            + x1.x*wo[4] + x1.y*wo[5] + x1.z*wo[6] + x1.w*wo[7];
                }
            }
        }
    }
    if (p < 400) {
        #pragma unroll
        for (int o = 0; o < 16; ++o)
            y[b*12800 + (og+o)*400 + p] = fmaxf(acc[o]*(1.f/255.f) + bb[og+o], 0.f);
    }
}

// ---------------- conv2: (32,20,20)->(64,9,9) k4 s2 relu, parity-split LDS --
// 2 blocks per image (32 oc each) -> 2 blocks/CU.
__global__ __launch_bounds__(512, 4) void k_conv2(const float* __restrict__ h1,
                                                  const float* __restrict__ w2,
                                                  const float* __restrict__ b2,
                                                  float* __restrict__ h2) {
    int blk = blockIdx.x, tid = threadIdx.x;
    int b = blk >> 1, og = (blk & 1) << 5;
    __shared__ float hl[12800];
    for (int i = tid; i < 12800; i += 512) {
        int ci = i / 400, pix = i % 400, iy = pix / 20, ix = pix % 20;
        hl[ci*400 + ((iy&1)*2 + (ix&1))*100 + (iy>>1)*10 + (ix>>1)] = h1[b*12800 + i];
    }
    __syncthreads();
    for (int idx = tid; idx < 2592; idx += 512) {
        int o = og + idx/81, p = idx%81, oy = p/9, ox = p%9;
        float acc = 0.f;
        const float* wo = w2 + o*512;
        for (int ci = 0; ci < 32; ci++) {
            const float* base = hl + ci*400;
            const float* wb = wo + ci*16;
            #pragma unroll
            for (int ky = 0; ky < 4; ky++)
            #pragma unroll
            for (int kx = 0; kx < 4; kx++)
                acc += base[((ky&1)*2 + (kx&1))*100 + (oy + (ky>>1))*10 + (ox + (kx>>1))]
                     * wb[ky*4 + kx];
        }
        h2[b*5184 + o*81 + p] = fmaxf(acc + b2[o], 0.f);
    }
}

// ---------------- bias = circ_conv3x3(h2, U_w) + U_b ------------------------
// 2 blocks per image (32 oc each) -> light LDS, high occupancy.
__global__ __launch_bounds__(512, 4) void k_bias(const float* __restrict__ h2,
                                                 const float* __restrict__ Uw,
                                                 const float* __restrict__ Ub,
                                                 float* __restrict__ bias) {
    int blk = blockIdx.x, tid = threadIdx.x;
    int b = blk >> 1, og = (blk & 1) << 5;
    __shared__ float h2l[5184];
    for (int i = tid; i < 5184; i += 512) h2l[i] = h2[b*5184 + i];
    __syncthreads();
    for (int idx = tid; idx < 2592; idx += 512) {
        int o = og + idx/81, p = idx%81, i0 = p/9, j0 = p%9;
        int im = (i0+8)%9, ip = (i0+1)%9, jm = (j0+8)%9, jp = (j0+1)%9;
        int r0 = im*9, r1 = i0*9, r2 = ip*9;
        float acc = 0.f;
        const float* wo = Uw + o*576;
        for (int ci = 0; ci < 64; ci++) {
            const float* hb = h2l + ci*81;
            const float* wb = wo + ci*9;
            acc += hb[r0+jm]*wb[0] + hb[r0+j0]*wb[1] + hb[r0+jp]*wb[2]
                 + hb[r1+jm]*wb[3] + hb[r1+j0]*wb[4] + hb[r1+jp]*wb[5]
                 + hb[r2+jm]*wb[6] + hb[r2+j0]*wb[7] + hb[r2+jp]*wb[8];
        }
        bias[b*5184 + o*81 + p] = acc + Ub[o];
    }
}

// ---------------- Af(f) for canonical f only -------------------------------
__global__ __launch_bounds__(256) void k_af(const float* __restrict__ Aw,
                                            const float* __restrict__ sc,
                                            float2* __restrict__ Af) {
    int l = blockIdx.x; int f = CANON(l);
    int x = f/9, y = f%9;
    float inv = sc[1];
    for (int pr = threadIdx.x; pr < 4096; pr += 256) {
        const float* a = Aw + pr*9;
        float re = 0.f, im = 0.f;
        #pragma unroll
        for (int dx = 0; dx < 3; dx++)
        #pragma unroll
        for (int dy = 0; dy < 3; dy++) {
            int tt = (x*(dx+8) + y*(dy+8)) % 9;
            float v = a[dx*3+dy] * inv;
            re += v * COS9[tt]; im += v * SIN9[tt];
        }
        Af[f*4096 + pr] = make_float2(re, im);
    }
}

// ---------------- M = 1.1 I + g A^H A ; W^T = (0.9 I - g A^H A)^T ----------
__global__ __launch_bounds__(256) void k_mw(const float2* __restrict__ Af,
                                            const float* __restrict__ gp,
                                            float2* __restrict__ Mmat,
                                            float2* __restrict__ WmT) {
    int l = blockIdx.x; int f = CANON(l);
    float g = gp[0];
    __shared__ float2 Al[4096];
    for (int i = threadIdx.x; i < 4096; i += 256) Al[i] = Af[f*4096 + i];
    __syncthreads();
    for (int e = threadIdx.x; e < 4096; e += 256) {
        int i = e >> 6, j = e & 63;
        float sr = 0.f, si = 0.f;
        for (int o = 0; o < 64; o++) {
            float2 a = Al[o*64 + i], b = Al[o*64 + j];
            sr += a.x*b.x + a.y*b.y;
            si += a.x*b.y - a.y*b.x;
        }
        Mmat[f*4096 + e] = make_float2((i==j ? 1.1f : 0.f) + g*sr, g*si);
        WmT [f*4096 + j*64 + i] = make_float2((i==j ? 0.9f : 0.f) - g*sr, -g*si);
    }
}

// ---------------- in-place Gauss-Jordan inverse, conflict-free -------------
__global__ __launch_bounds__(256) void k_inv(float2* __restrict__ Mio) {
    int l = blockIdx.x; int f = CANON(l);
    __shared__ float2 M[64*65];
    __shared__ float2 rowk[64];
    __shared__ float2 fcol[64];
    int tid = threadIdx.x;
    float2* Mg = Mio + f*4096;
    for (int e = tid; e < 4096; e += 256) M[(e>>6)*65 + (e&63)] = Mg[e];
    __syncthreads();
    int j = tid & 63, ig = tid >> 6;
    for (int k = 0; k < 64; k++) {
        if (ig == 0) {
            float2 d = M[k*65 + k];
            float den = 1.f / (d.x*d.x + d.y*d.y);
            float pr = d.x*den, pi = -d.y*den;
            float2 m = M[k*65 + j];
            rowk[j] = (j == k) ? make_float2(pr, pi)
                               : make_float2(m.x*pr - m.y*pi, m.x*pi + m.y*pr);
        } else if (ig == 1) {
            fcol[j] = M[j*65 + k];
        }
        __syncthreads();
        #pragma unroll 4
        for (int s = 0; s < 16; s++) {
            int i = (ig << 4) + s;
            if (i == k) {
                M[i*65 + j] = rowk[j];
            } else {
                float2 fi = fcol[i];
                if (j == k) {
                    float2 rk = rowk[k];
                    M[i*65 + j] = make_float2(-(fi.x*rk.x - fi.y*rk.y),
                                              -(fi.x*rk.y + fi.y*rk.x));
                } else {
                    float2 r = rowk[j]; float2 m = M[i*65 + j];
                    M[i*65 + j] = make_float2(m.x - (fi.x*r.x - fi.y*r.y),
                                              m.y - (fi.x*r.y + fi.y*r.x));
                }
            }
        }
        __syncthreads();
    }
    for (int e = tid; e < 4096; e += 256) {
        int i2 = e >> 6, j2 = e & 63;
        Mio[f*4096 + j2*64 + i2] = M[i2*65 + j2];
    }
}

// ---------------- prologue FFT: Tf = FFT2(bias), register-blocked ----------
__global__ __launch_bounds__(192) void k_fft(const float* __restrict__ in,
                                             float2* __restrict__ Tf) {
    __shared__ float2 T1[16*83];
    int tid = threadIdx.x;
    int img = tid & 15, j = tid >> 4;         // j in [0,12), active j<9
    int gimg = blockIdx.x*16 + img;
    if (j < 9) {                               // FFT stage 1, row r=j
        int r = j;
        float tn[9];
        const float* gp = in + gimg*81 + r*9;
        #pragma unroll
        for (int xc = 0; xc < 9; ++xc) tn[xc] = gp[xc];
        #pragma unroll
        for (int ky = 0; ky < 9; ++ky) {
            float sr = 0.f, si = 0.f;
            #pragma unroll
            for (int xx = 0; xx < 9; ++xx) {
                const int m = (ky*xx) % 9;
                sr += tn[xx]*C9[m];
                si -= tn[xx]*S9[m];
            }
            T1[img*83 + r*9 + ky] = make_float2(sr, si);
        }
    }
    __syncthreads();
    if (j < 9) {                               // FFT stage 2, column ky=j
        int ky = j;
        float2 s[9];
        #pragma unroll
        for (int r = 0; r < 9; ++r) s[r] = T1[img*83 + r*9 + ky];
        #pragma unroll
        for (int kx = 0; kx < 5; ++kx) {
            float fr = 0.f, fi = 0.f;
            #pragma unroll
            for (int r = 0; r < 9; ++r) {
                const int m = (kx*r) % 9;
                fr += s[r].x*C9[m] + s[r].y*S9[m];
                fi += s[r].y*C9[m] - s[r].x*S9[m];
            }
            if (kx > 0 || ky < 5)
                Tf[(kx*9 + ky)*NIMG + gimg] = make_float2(fr, fi);
        }
    }
}

// ---------------- per-frequency matvec, LDS-free, 16 chunks/freq -----------
__global__ __launch_bounds__(256) void k_mv(const float2* __restrict__ Tf,
                                            float2* __restrict__ Yf,
                                            const float2* __restrict__ V) {
    int l = blockIdx.x >> 4, bc = blockIdx.x & 15;   // 41 freqs x 16 chunks
    int f = CANON(l);
    int lane = threadIdx.x & 63;
    int wid  = __builtin_amdgcn_readfirstlane((int)(threadIdx.x >> 6));
    int b0 = bc*16 + wid*4;                          // 4 batches per wave
    const float2* Vg = V + f*4096 + lane;
    const float2* Tg = Tf + f*NIMG + b0*64;
    float2 a0 = make_float2(0.f,0.f), a1 = a0, a2 = a0, a3 = a0;
    #pragma unroll 8
    for (int c = 0; c < 64; ++c) {
        float2 v = Vg[c*64];
        float2 t0 = Tg[c], t1 = Tg[64+c], t2 = Tg[128+c], t3 = Tg[192+c];
        a0.x += v.x*t0.x - v.y*t0.y; a0.y += v.x*t0.y + v.y*t0.x;
        a1.x += v.x*t1.x - v.y*t1.y; a1.y += v.x*t1.y + v.y*t1.x;
        a2.x += v.x*t2.x - v.y*t2.y; a2.y += v.x*t2.y + v.y*t2.x;
        a3.x += v.x*t3.x - v.y*t3.y; a3.y += v.x*t3.y + v.y*t3.x;
    }
    float2* Yg = Yf + f*NIMG + b0*64 + lane;
    Yg[0] = a0; Yg[64] = a1; Yg[128] = a2; Yg[192] = a3;
}

// ---------------- fused iteration: IFFT2 + PR update + FFT2 ----------------
__global__ __launch_bounds__(192) void k_fuse(const float2* __restrict__ Yf,
                                              float* __restrict__ u12g,
                                              const float* __restrict__ bias,
                                              float2* __restrict__ Tf,
                                              int last) {
    __shared__ float2 T1[16*83];
    int tid = threadIdx.x;
    int img = tid & 15, j = tid >> 4;
    int gimg = blockIdx.x*16 + img;
    // ---- phase 1: load Yf (mirror conj) + IFFT stage 1, column ky=j ----
    if (j < 9) {
        int ky = j;
        float2 y[9];
        #pragma unroll
        for (int kx = 0; kx < 9; ++kx) {
            int fc; bool cj;
            if (kx == 0)      { cj = (ky >= 5); fc = cj ? (9 - ky) : ky; }
            else if (kx <= 4) { cj = false;     fc = kx*9 + ky; }
            else              { cj = true;      fc = (9-kx)*9 + (ky ? 9-ky : 0); }
            float2 a = Yf[fc*NIMG + gimg];
            y[kx] = make_float2(a.x, cj ? -a.y : a.y);
        }
        #pragma unroll
        for (int r = 0; r < 9; ++r) {
            float sr = 0.f, si = 0.f;
            #pragma unroll
            for (int kx = 0; kx < 9; ++kx) {
                const int m = (r*kx) % 9;
                sr += y[kx].x*C9[m] - y[kx].y*S9[m];
                si += y[kx].x*S9[m] + y[kx].y*C9[m];
            }
            T1[img*83 + r*9 + ky] = make_float2(sr, si);
        }
    }
    __syncthreads();
    // ---- phase 2: IFFT st2 + PR update + FFT st1, row r=j (in-place) ----
    if (j < 9) {
        int r = j;
        float2 t1[9];
        #pragma unroll
        for (int ky = 0; ky < 9; ++ky) t1[ky] = T1[img*83 + r*9 + ky];
        float tn[9];
        int gb = gimg*81 + r*9;
        #pragma unroll
        for (int xc = 0; xc < 9; ++xc) {
            float yr = 0.f;
            #pragma unroll
            for (int ky = 0; ky < 9; ++ky) {
                const int m = (xc*ky) % 9;
                yr += t1[ky].x*C9[m] - t1[ky].y*S9[m];
            }
            yr *= (1.f/81.f);
            float u12v = u12g[gb + xc];
            float un = 2.f*yr - u12v;
            bool interior = (r >= 1 && r <= 7 && xc >= 1 && xc <= 7);
            float zn = interior ? fmaxf(un, 0.f) : 0.f;
            float u12n = 2.f*zn - un;
            u12g[gb + xc] = u12n;
            tn[xc] = last ? zn : (u12n + bias[gb + xc]);
        }
        #pragma unroll
        for (int ky = 0; ky < 9; ++ky) {
            float sr = 0.f, si = 0.f;
            #pragma unroll
            for (int xx = 0; xx < 9; ++xx) {
                const int m = (ky*xx) % 9;
                sr += tn[xx]*C9[m];
                si -= tn[xx]*S9[m];
            }
            T1[img*83 + r*9 + ky] = make_float2(sr, si);
        }
    }
    __syncthreads();
    // ---- phase 3: FFT st2, canonical freqs only, column ky=j ----
    if (j < 9) {
        int ky = j;
        float2 s[9];
        #pragma unroll
        for (int r = 0; r < 9; ++r) s[r] = T1[img*83 + r*9 + ky];
        #pragma unroll
        for (int kx = 0; kx < 5; ++kx) {
            float fr = 0.f, fi = 0.f;
            #pragma unroll
            for (int r = 0; r < 9; ++r) {
                const int m = (kx*r) % 9;
                fr += s[r].x*C9[m] + s[r].y*S9[m];
                fi += s[r].y*C9[m] - s[r].x*S9[m];
            }
            if (kx > 0 || ky < 5)
                Tf[(kx*9 + ky)*NIMG + gimg] = make_float2(fr, fi);
        }
    }
}

// ---------------- final: IFFT(W z) -> relu(+bias) -> crop write ------------
__global__ __launch_bounds__(192) void k_crop(const float2* __restrict__ Yf,
                                              const float* __restrict__ bias,
                                              float* __restrict__ zc) {
    __shared__ float2 T1[16*83];
    int tid = threadIdx.x;
    int img = tid & 15, j = tid >> 4;
    int gimg = blockIdx.x*16 + img;
    if (j < 9) {                               // mirror-load + IFFT st1
        int ky = j;
        float2 y[9];
        #pragma unroll
        for (int kx = 0; kx < 9; ++kx) {
            int fc; bool cj;
            if (kx == 0)      { cj = (ky >= 5); fc = cj ? (9 - ky) : ky; }
            else if (kx <= 4) { cj = false;     fc = kx*9 + ky; }
            else              { cj = true;      fc = (9-kx)*9 + (ky ? 9-ky : 0); }
            float2 a = Yf[fc*NIMG + gimg];
            y[kx] = make_float2(a.x, cj ? -a.y : a.y);
        }
        #pragma unroll
        for (int r = 0; r < 9; ++r) {
            float sr = 0.f, si = 0.f;
            #pragma unroll
            for (int kx = 0; kx < 9; ++kx) {
                const int m = (r*kx) % 9;
                sr += y[kx].x*C9[m] - y[kx].y*S9[m];
                si += y[kx].x*S9[m] + y[kx].y*C9[m];
            }
            T1[img*83 + r*9 + ky] = make_float2(sr, si);
        }
    }
    __syncthreads();
    if (j >= 1 && j <= 7) {                    // IFFT st2 + relu + crop, row r=j
        int r = j;
        float2 t1[9];
        #pragma unroll
        for (int ky = 0; ky < 9; ++ky) t1[ky] = T1[img*83 + r*9 + ky];
        int gb = gimg*81 + r*9;
        float* zr = zc + (gimg >> 6)*3136 + (gimg & 63)*49 + (r-1)*7;
        #pragma unroll
        for (int xc = 1; xc < 8; ++xc) {
            float yr = 0.f;
            #pragma unroll
            for (int ky = 0; ky < 9; ++ky) {
                const int m = (xc*ky) % 9;
                yr += t1[ky].x*C9[m] - t1[ky].y*S9[m];
            }
            yr *= (1.f/81.f);
            zr[xc-1] = fmaxf(yr + bias[gb + xc], 0.f);
        }
    }
}

// ---------------- fc1: (256x3136)x(512x3136)^T + b, relu -------------------
__global__ __launch_bounds__(256) void k_fc1(const float* __restrict__ A,
                                             const float* __restrict__ W,
                                             const float* __restrict__ bb,
                                             float* __restrict__ H) {
    int bt = blockIdx.x >> 5, ot = blockIdx.x & 31;
    int b0 = bt*16, o0 = ot*16;
    __shared__ float At[16][65], Bt[16][65];
    int tid = threadIdx.x;
    int row = tid >> 6, col = tid & 63;
    int tb = tid >> 4, to = tid & 15;
    float acc = 0.f;
    for (int k0 = 0; k0 < 3136; k0 += 64) {
        #pragma unroll
        for (int s = 0; s < 4; s++) {
            int rr = row + s*4;
            At[rr][col] = A[(b0+rr)*3136 + k0 + col];
            Bt[rr][col] = W[(o0+rr)*3136 + k0 + col];
        }
        __syncthreads();
        #pragma unroll
        for (int kk = 0; kk < 64; kk++)
            acc += At[tb][kk] * Bt[to][kk];
        __syncthreads();
    }
    H[(b0+tb)*512 + o0+to] = fmaxf(acc + bb[o0+to], 0.f);
}

// ---------------- fc2: (256x512)x(18x512)^T + b ----------------------------
__global__ __launch_bounds__(256) void k_fc2(const float* __restrict__ H,
                                             const float* __restrict__ W,
                                             const float* __restrict__ bb,
                                             float* __restrict__ out) {
    int idx = blockIdx.x*256 + threadIdx.x;
    if (idx >= 4608) return;
    int b = idx/18, o = idx%18;
    const float* h = H + b*512;
    const float* w = W + o*512;
    float acc = 0.f;
    for (int k = 0; k < 512; k++) acc += h[k]*w[k];
    out[idx] = acc + bb[o];
}

// ---------------------------------------------------------------------------
extern "C" void kernel_launch(void* const* d_in, const int* in_sizes, int n_in,
                              void* d_out, int out_size, void* d_ws, size_t ws_size,
                              hipStream_t stream) {
    (void)in_sizes; (void)n_in; (void)out_size; (void)ws_size;
    const float* x   = (const float*)d_in[0];
    const float* c1w = (const float*)d_in[1];
    const float* c1b = (const float*)d_in[2];
    const float* c2w = (const float*)d_in[3];
    const float* c2b = (const float*)d_in[4];
    const float* Uw  = (const float*)d_in[5];
    const float* Ub  = (const float*)d_in[6];
    const float* Aw  = (const float*)d_in[7];
    const float* gp  = (const float*)d_in[8];
    const float* f1w = (const float*)d_in[9];
    const float* f1b = (const float*)d_in[10];
    const float* f2w = (const float*)d_in[11];
    const float* f2b = (const float*)d_in[12];

    float* ws = (float*)d_ws;
    float*  h1   = ws + 0;                       // 3,276,800 f
    float2* Tf   = (float2*)(ws + 0);            // alias h1 (dead after conv2)
    float*  bias = ws + 3276800;                 // 1,327,104 f
    float*  u12  = ws + 4603904;                 // 1,327,104 f
    float2* Yf   = (float2*)(ws + 5931008);      // 1,327,104 c2
    float2* Af   = (float2*)(ws + 8585216);      // 331,776 c2
    float2* Minv = (float2*)(ws + 9248768);      // 331,776 c2
    float2* WmT  = (float2*)(ws + 9912320);      // 331,776 c2
    float*  zc   = ws + 10575872;                // 802,816 f
    float*  hfc  = ws + 11378688;                // 131,072 f
    float*  sc   = ws + 11509760;                // 2 f
    float*  h2   = ws + 11509764;                // 1,327,104 f

    hipMemsetAsync(u12, 0, (size_t)1327104*sizeof(float), stream);

    k_norm <<<1,   256, 0, stream>>>(Aw, sc);
    k_conv1<<<512, 512, 0, stream>>>(x, c1w, c1b, h1);
    k_conv2<<<512, 512, 0, stream>>>(h1, c2w, c2b, h2);
    k_bias <<<512, 512, 0, stream>>>(h2, Uw, Ub, bias);
    k_af   <<<NCAN,256, 0, stream>>>(Aw, sc, Af);
    k_mw   <<<NCAN,256, 0, stream>>>(Af, gp, Minv, WmT);
    k_inv  <<<NCAN,256, 0, stream>>>(Minv);

    // iteration 0 forward: u12 = 0, so T = FFT(bias)
    k_fft<<<1024,192,0,stream>>>(bias, Tf);
    for (int it = 0; it < MAXIT; it++) {
        k_mv  <<<NCAN*16,256,0,stream>>>(Tf, Yf, Minv);
        k_fuse<<<1024,   192,0,stream>>>(Yf, u12, bias, Tf, it == MAXIT-1);
    }
    // final pass: brelu(W z + bias) -> crop  (Tf already = FFT(z))
    k_mv  <<<NCAN*16,256,0,stream>>>(Tf, Yf, WmT);
    k_crop<<<1024,   192,0,stream>>>(Yf, bias, zc);

    k_fc1<<<512,256,0,stream>>>(zc, f1w, f1b, hfc);
    k_fc2<<<18, 256,0,stream>>>(hfc, f2w, f2b, (float*)d_out);
}